// Round 14
// baseline (243.492 us; speedup 1.0000x reference)
//
#include <hip/hip_runtime.h>
#include <hip/hip_bf16.h>

// SimilarityLayer: out[e,q,w,n,m] = <p[e,w,:,n], q[e,q,:,m]> / (|p||q| + 1e-8)
// E=8 W=5 C=640 N=49 Q=75.
// R14: fused R9 structure (best 38.8us) with B staging rebuilt for VMEM
//      throughput: query chunk is CONTIGUOUS -> 392 coalesced float4 into fp32
//      LDS (double-buffered), per-thread fragment build = 16 ds_read_b32 at
//      stride 49 (exact 2-way bank alias = free) + in-reg cvt. 600 blocks
//      (e,q), 512 thr / 8 waves = 4 row-groups x 2 col-groups (query staged
//      once, no mh duplication). A-frags from aimg, static parity indexing
//      (no R10 spill). Raw lgkm-only barrier per chunk; GLOAD(c+2) in flight.

#define E_CNT 8
#define W_CNT 5
#define C_CNT 640
#define N_CNT 49
#define Q_CNT 75
#define MROWS 245                    // W*N
#define NC32 20                      // K chunks of 32
#define CHF 1568                     // floats per B chunk (32 x 49)
#define NF4 392                      // float4s per chunk
#define AFRAG_CH 16384               // per (e,chunk): 16 row-tiles x 64 lanes x 16B
#define AIMG_E (NC32 * AFRAG_CH)     // 327,680 B per e
#define AIMG_SIZE (E_CNT * AIMG_E)   // 2,621,440
#define PN_OFF AIMG_SIZE
#define PN_BYTES (E_CNT * 10 * MROWS * 4)
#define WS1 ((size_t)(PN_OFF + PN_BYTES))

typedef __attribute__((ext_vector_type(8))) short bf16x8;
typedef __attribute__((ext_vector_type(4))) float f32x4;

static __device__ __forceinline__ short f2bf(float f) {
    __hip_bfloat16 h = __float2bfloat16(f);
    return *reinterpret_cast<short*>(&h);
}

// Raw barrier WITHOUT vmcnt drain: LDS visibility only; global loads in flight.
#define RAW_BARRIER() asm volatile("s_waitcnt lgkmcnt(0)\n\ts_barrier" ::: "memory")

// ---------------- prep_a: proto -> fragment-ordered bf16 A image + partials --
__global__ __launch_bounds__(256, 4)
void prep_a_kernel(const float* __restrict__ proto,
                   unsigned char* __restrict__ aimg,
                   float* __restrict__ pn_part)
{
    __shared__ float pns[MROWS];
    const int b = blockIdx.x;            // 80 = e*10 + c64
    const int e = b / 10, c64 = b % 10;
    const float* pbase = proto + (size_t)e * (W_CNT * C_CNT * N_CNT);
    unsigned char* ebase = aimg + (size_t)e * AIMG_E;
    const int t = threadIdx.x;
    if (t < MROWS) pns[t] = 0.f;
    __syncthreads();

    #pragma unroll
    for (int i = 0; i < 8; ++i) {
        const int s = t + i * 256;       // slot = kb*245 + nw, kb in [0,8)
        int nw, kb;
        bf16x8 pk;
        if (s < 8 * MROWS) {
            kb = s / MROWS;
            nw = s - kb * MROWS;
            const int w = nw / N_CNT, n = nw - w * N_CNT;
            const float* g = pbase + ((size_t)(w * C_CNT + c64 * 64 + kb * 8)) * N_CNT + n;
            float ss = 0.f;
            #pragma unroll
            for (int j = 0; j < 8; ++j) {
                const float f = g[(size_t)j * N_CNT];
                ss += f * f;
                pk[j] = f2bf(f);
            }
            atomicAdd(&pns[nw], ss);
        } else {
            const int x = s - 8 * MROWS; // zero-pad rows 245..255
            nw = MROWS + (x >> 3);
            kb = x & 7;
            pk = (bf16x8){0, 0, 0, 0, 0, 0, 0, 0};
        }
        const int c32 = c64 * 2 + (kb >> 2);
        const int ln2 = ((kb & 3) << 4) | (nw & 15);
        *reinterpret_cast<bf16x8*>(
            ebase + (size_t)c32 * AFRAG_CH + (size_t)((nw >> 4) * 64 + ln2) * 16) = pk;
    }
    __syncthreads();
    if (t < MROWS) pn_part[(size_t)(e * 10 + c64) * MROWS + t] = pns[t];
}

// ---------------- gemm8: coalesced fp32-LDS B + direct frag build ------------
__global__ __launch_bounds__(512, 4)
void gemm8_kernel(const float* __restrict__ query,
                  const unsigned char* __restrict__ aimg,
                  const float* __restrict__ pn_part,
                  float* __restrict__ out)
{
    __shared__ __align__(16) float fbuf[2][CHF];   // fp32 chunk, double-buffered
    __shared__ float qn[64];
    __shared__ float pnl[256];

    const int b = blockIdx.x;            // 600
    const int e = b & 7;                 // same e -> same XCD -> aimg L2-hot
    const int q = b >> 3;
    const int eq = e * Q_CNT + q;
    const int t = threadIdx.x;
    const int wv = t >> 6, ln = t & 63;
    const int lrow = ln & 15, lk = ln >> 4;
    const int rg = wv >> 1;              // row-group 0..3: rows [rg*64, +64)
    const int cg = wv & 1;               // col-group 0..1: cols [cg*32, +32)

    const f32x4* __restrict__ qsl4 =
        reinterpret_cast<const f32x4*>(query + (size_t)eq * (C_CNT * N_CNT));

    // A fragments: this wave's 4 row-tiles (rt = rg*4 + fi)
    const unsigned char* __restrict__ abase =
        aimg + (size_t)e * AIMG_E + (size_t)(rg * 4 * 64 + ln) * 16;

    // this wave's 2 columns (fjj = 0,1): col = cg*32 + fjj*16 + lrow
    int colc[2];
    #pragma unroll
    for (int fjj = 0; fjj < 2; ++fjj) {
        const int c_ = cg * 32 + fjj * 16 + lrow;
        colc[fjj] = (c_ < N_CNT) ? c_ : (N_CNT - 1);   // clamp; masked at write
    }

    // p-norms (hazard covered by in-loop barriers)
    if (t < MROWS) {
        float s = 0.f;
        #pragma unroll
        for (int cc = 0; cc < 10; ++cc)
            s += pn_part[(size_t)(e * 10 + cc) * MROWS + t];
        pnl[t] = sqrtf(s);
    }

    const bool tld = t < NF4;            // 392 stagers
    f32x4 vq[2];                         // static parity only
    bf16x8 afr[2][4];                    // static parity only
    f32x4 acc[4][2];
    #pragma unroll
    for (int i = 0; i < 4; ++i)
        #pragma unroll
        for (int j = 0; j < 2; ++j) acc[i][j] = (f32x4){0.f, 0.f, 0.f, 0.f};
    float ssq[2] = {0.f, 0.f};

#define G8_GLOAD(c) do {                                                        \
    if (tld) vq[(c) & 1] = qsl4[(size_t)(c) * NF4 + t];                         \
} while (0)

#define G8_FWRITE(c) do {                                                       \
    if (tld) *reinterpret_cast<f32x4*>(&fbuf[(c) & 1][t * 4]) = vq[(c) & 1];    \
} while (0)

#define G8_ALOAD(c) do {                                                        \
    _Pragma("unroll")                                                           \
    for (int fi_ = 0; fi_ < 4; ++fi_)                                           \
        afr[(c) & 1][fi_] = *reinterpret_cast<const bf16x8*>(                   \
            abase + (size_t)(c) * AFRAG_CH + fi_ * 1024);                       \
} while (0)

    // prologue: chunk 0 staged; chunk 1 loads in flight
    G8_GLOAD(0);
    G8_ALOAD(0);
    G8_FWRITE(0);
    G8_GLOAD(1);
    RAW_BARRIER();

    #pragma unroll
    for (int c = 0; c < NC32; ++c) {     // fully unrolled: all parities static
        if (c + 2 < NC32) G8_GLOAD(c + 2);        // into vq[c&1] (consumed below... at c-1)
        if (c + 1 < NC32) { G8_ALOAD(c + 1); G8_FWRITE(c + 1); }

        // build 2 B fragments from fp32 LDS (stride-49: exact 2-way alias, free)
        const float* __restrict__ bbf = fbuf[c & 1];
        bf16x8 bfr[2];
        #pragma unroll
        for (int fjj = 0; fjj < 2; ++fjj) {
            float s8 = 0.f;
            #pragma unroll
            for (int j = 0; j < 8; ++j) {
                const float f = bbf[(lk * 8 + j) * N_CNT + colc[fjj]];
                s8 += f * f;
                bfr[fjj][j] = f2bf(f);
            }
            ssq[fjj] += s8;
        }

        // MFMA: 4 row-tiles x 2 col-frags
        #pragma unroll
        for (int fi = 0; fi < 4; ++fi)
            #pragma unroll
            for (int fjj = 0; fjj < 2; ++fjj)
                acc[fi][fjj] = __builtin_amdgcn_mfma_f32_16x16x32_bf16(
                    afr[c & 1][fi], bfr[fjj], acc[fi][fjj], 0, 0, 0);

        RAW_BARRIER();
    }

    // ---- q-norms: reduce over lk groups; waves rg==0 (wv<2) publish ----
    #pragma unroll
    for (int fjj = 0; fjj < 2; ++fjj) {
        float s = ssq[fjj];
        s += __shfl_xor(s, 16);
        s += __shfl_xor(s, 32);
        if (wv < 2 && lk == 0) qn[cg * 32 + fjj * 16 + lrow] = s;
    }
    __syncthreads();

    // ---- epilogue: row = rg*64 + fi*16 + lk*4 + rr ; col = cg*32 + fjj*16 + lrow
    float nq2[2];
    #pragma unroll
    for (int fjj = 0; fjj < 2; ++fjj) {
        const int m = cg * 32 + fjj * 16 + lrow;
        nq2[fjj] = (m < N_CNT) ? sqrtf(qn[m]) : 1.f;
    }
    float* __restrict__ osl = out + (size_t)eq * (W_CNT * N_CNT * N_CNT);
    #pragma unroll
    for (int fi = 0; fi < 4; ++fi) {
        #pragma unroll
        for (int rr = 0; rr < 4; ++rr) {
            const int row = rg * 64 + fi * 16 + lk * 4 + rr;
            if (row < MROWS) {
                const float np_ = pnl[row];
                #pragma unroll
                for (int fjj = 0; fjj < 2; ++fjj) {
                    const int m = cg * 32 + fjj * 16 + lrow;
                    if (m < N_CNT) {
                        const float den = np_ * nq2[fjj] + 1e-8f;
                        osl[row * N_CNT + m] = acc[fi][fjj][rr] * __builtin_amdgcn_rcpf(den);
                    }
                }
            }
        }
    }
#undef G8_GLOAD
#undef G8_FWRITE
#undef G8_ALOAD
}

// ---------------- tier-0 fallback (R2 kernel, no ws) -------------------------
struct SMemFB {
    unsigned char A[256 * 128];
    unsigned char B[64 * 128];
    float ns[320];
};

__global__ __launch_bounds__(512, 4)
void sim_fallback_kernel(const float* __restrict__ proto,
                         const float* __restrict__ query,
                         float* __restrict__ out)
{
    __shared__ SMemFB smf;
    const int t = threadIdx.x;
    const int e = blockIdx.x / Q_CNT;
    const int q = blockIdx.x - e * Q_CNT;
    const float* pbase = proto + (size_t)e * (W_CNT * C_CNT * N_CNT);
    const float* qbase = query + ((size_t)e * Q_CNT + q) * (C_CNT * N_CNT);
    unsigned char* lds = (unsigned char*)&smf;
    if (t < 320) smf.ns[t] = 0.f;
    if (t < 208) {
        if (t < 88) *reinterpret_cast<f32x4*>(smf.A + 245 * 128 + t * 16) = (f32x4){0.f,0.f,0.f,0.f};
        else        *reinterpret_cast<f32x4*>(smf.B + 49 * 128 + (t - 88) * 16) = (f32x4){0.f,0.f,0.f,0.f};
    }
    const int nslot5 = (t < 304);
    const float* gp[5];
    int offidx[5];
    #pragma unroll
    for (int i = 0; i < 5; ++i) {
        gp[i] = pbase; offidx[i] = 0;
        if (i < 4 || nslot5) {
            const int s = t + i * 512;
            if (s < 1960) {
                const int kb = s / 245, nw = s - kb * 245;
                const int w = nw / 49, n = nw - w * 49;
                gp[i] = pbase + ((size_t)w * C_CNT + kb * 8) * N_CNT + n;
                offidx[i] = (nw * 128 + ((kb ^ (nw & 7)) << 4)) | (nw << 16);
            } else {
                const int s2 = s - 1960;
                const int kb = s2 / 49, mq = s2 - kb * 49;
                gp[i] = qbase + (size_t)(kb * 8) * N_CNT + mq;
                offidx[i] = (32768 + mq * 128 + ((kb ^ (mq & 7)) << 4)) | ((256 + mq) << 16);
            }
        }
    }
    float v[5][8];
    float ss[5] = {0.f,0.f,0.f,0.f,0.f};
    #pragma unroll
    for (int i = 0; i < 4; ++i)
        #pragma unroll
        for (int j = 0; j < 8; ++j) v[i][j] = gp[i][(size_t)j * N_CNT];
    if (nslot5)
        #pragma unroll
        for (int j = 0; j < 8; ++j) v[4][j] = gp[4][(size_t)j * N_CNT];
    f32x4 acc[2][4];
    #pragma unroll
    for (int i = 0; i < 2; ++i)
        #pragma unroll
        for (int j = 0; j < 4; ++j) acc[i][j] = (f32x4){0.f,0.f,0.f,0.f};
    const int wv = t >> 6, ln = t & 63, lrow = ln & 15, lk = ln >> 4;
    for (int kc = 0; kc < 10; ++kc) {
        #pragma unroll
        for (int i = 0; i < 5; ++i) {
            if (i < 4 || nslot5) {
                bf16x8 pk; float s8 = 0.f;
                #pragma unroll
                for (int j = 0; j < 8; ++j) { const float f = v[i][j]; s8 += f*f; pk[j] = f2bf(f); }
                ss[i] += s8;
                *reinterpret_cast<bf16x8*>(lds + (offidx[i] & 0xFFFF)) = pk;
            }
        }
        __syncthreads();
        if (kc < 9) {
            #pragma unroll
            for (int i = 0; i < 4; ++i) {
                gp[i] += 64 * N_CNT;
                #pragma unroll
                for (int j = 0; j < 8; ++j) v[i][j] = gp[i][(size_t)j * N_CNT];
            }
            if (nslot5) {
                gp[4] += 64 * N_CNT;
                #pragma unroll
                for (int j = 0; j < 8; ++j) v[4][j] = gp[4][(size_t)j * N_CNT];
            }
        }
        #pragma unroll
        for (int ks = 0; ks < 2; ++ks) {
            bf16x8 af[2], bfr[4];
            #pragma unroll
            for (int i = 0; i < 2; ++i) {
                const int row = (wv * 2 + i) * 16 + lrow;
                const int gr = (ks * 4 + lk) ^ (row & 7);
                af[i] = *reinterpret_cast<const bf16x8*>(lds + row * 128 + gr * 16);
            }
            #pragma unroll
            for (int j = 0; j < 4; ++j) {
                const int mq = j * 16 + lrow;
                const int gr = (ks * 4 + lk) ^ (mq & 7);
                bfr[j] = *reinterpret_cast<const bf16x8*>(lds + 32768 + mq * 128 + gr * 16);
            }
            #pragma unroll
            for (int i = 0; i < 2; ++i)
                #pragma unroll
                for (int j = 0; j < 4; ++j)
                    acc[i][j] = __builtin_amdgcn_mfma_f32_16x16x32_bf16(af[i], bfr[j], acc[i][j], 0, 0, 0);
        }
        __syncthreads();
    }
    #pragma unroll
    for (int i = 0; i < 5; ++i)
        if (i < 4 || nslot5) atomicAdd(&smf.ns[offidx[i] >> 16], ss[i]);
    __syncthreads();
    float nq[4];
    #pragma unroll
    for (int j = 0; j < 4; ++j) {
        const int mq = j * 16 + lrow;
        nq[j] = (mq < N_CNT) ? sqrtf(smf.ns[256 + mq]) : 1.f;
    }
    float* obase = out + (size_t)(e * Q_CNT + q) * (W_CNT * N_CNT * N_CNT);
    #pragma unroll
    for (int i = 0; i < 2; ++i) {
        #pragma unroll
        for (int rr = 0; rr < 4; ++rr) {
            const int nw = (wv * 2 + i) * 16 + lk * 4 + rr;
            if (nw < W_CNT * N_CNT) {
                const int w = nw / 49, n = nw - w * 49;
                const float np_ = sqrtf(smf.ns[nw]);
                float* orow = obase + ((size_t)w * N_CNT + n) * N_CNT;
                #pragma unroll
                for (int j = 0; j < 4; ++j) {
                    const int mq = j * 16 + lrow;
                    if (mq < N_CNT) orow[mq] = acc[i][j][rr] / (np_ * nq[j] + 1e-8f);
                }
            }
        }
    }
}

extern "C" void kernel_launch(void* const* d_in, const int* in_sizes, int n_in,
                              void* d_out, int out_size, void* d_ws, size_t ws_size,
                              hipStream_t stream)
{
    const float* proto = (const float*)d_in[0];
    const float* query = (const float*)d_in[1];
    float* out = (float*)d_out;

    if (ws_size < WS1) {
        hipLaunchKernelGGL(sim_fallback_kernel, dim3(E_CNT * Q_CNT), dim3(512), 0, stream,
                           proto, query, out);
        return;
    }

    unsigned char* aimg = (unsigned char*)d_ws;
    float* pn_part = (float*)((unsigned char*)d_ws + PN_OFF);

    hipLaunchKernelGGL(prep_a_kernel, dim3(E_CNT * 10), dim3(256), 0, stream,
                       proto, aimg, pn_part);
    hipLaunchKernelGGL(gemm8_kernel, dim3(E_CNT * Q_CNT), dim3(512), 0, stream,
                       query, aimg, pn_part, out);
}

// Round 15
// 42.945 us; speedup vs baseline: 5.6699x; 5.6699x over previous
//
#include <hip/hip_runtime.h>
#include <hip/hip_bf16.h>

// SimilarityLayer: out[e,q,w,n,m] = <p[e,w,:,n], q[e,q,:,m]> / (|p||q| + 1e-8)
// E=8 W=5 C=640 N=49 Q=75.
// R15: R9/R12's proven mechanics (best 38.8us, no spill) with the mh-split
//      removed: 600 blocks x 512 thr (8 waves x 32-row tiles = all 245 rows),
//      only threads t<256 stage B (same granule scheme) -> grid-level B VMEM
//      halved. Spill-proof by construction: runtime cc+=2 loop with NAMED
//      even/odd buffers (vBA/vBB, afrA/afrB, Bbuf0/Bbuf1) -- no register-array
//      indexing that depends on unroll success (R10/R11/R14 lesson).
//      Raw lgkm-only barriers (R12): prefetches stay in flight.

#define E_CNT 8
#define W_CNT 5
#define C_CNT 640
#define N_CNT 49
#define Q_CNT 75
#define MROWS 245                    // W*N
#define NC32 20                      // K chunks of 32
#define AFRAG_CH 16384               // per (e,chunk): 16 row-tiles x 64 lanes x 16B
#define AIMG_E (NC32 * AFRAG_CH)     // 327,680 B per e
#define AIMG_SIZE (E_CNT * AIMG_E)   // 2,621,440
#define PN_OFF AIMG_SIZE
#define PN_BYTES (E_CNT * 10 * MROWS * 4)
#define WS1 ((size_t)(PN_OFF + PN_BYTES))

typedef __attribute__((ext_vector_type(8))) short bf16x8;
typedef __attribute__((ext_vector_type(4))) float f32x4;

static __device__ __forceinline__ short f2bf(float f) {
    __hip_bfloat16 h = __float2bfloat16(f);
    return *reinterpret_cast<short*>(&h);
}

// Raw barrier WITHOUT vmcnt drain: LDS visibility only; global loads in flight.
#define RAW_BARRIER() asm volatile("s_waitcnt lgkmcnt(0)\n\ts_barrier" ::: "memory")

// ---------------- prep_a: proto -> fragment-ordered bf16 A image + partials --
__global__ __launch_bounds__(256, 4)
void prep_a_kernel(const float* __restrict__ proto,
                   unsigned char* __restrict__ aimg,
                   float* __restrict__ pn_part)
{
    __shared__ float pns[MROWS];
    const int b = blockIdx.x;            // 80 = e*10 + c64
    const int e = b / 10, c64 = b % 10;
    const float* pbase = proto + (size_t)e * (W_CNT * C_CNT * N_CNT);
    unsigned char* ebase = aimg + (size_t)e * AIMG_E;
    const int t = threadIdx.x;
    if (t < MROWS) pns[t] = 0.f;
    __syncthreads();

    #pragma unroll
    for (int i = 0; i < 8; ++i) {
        const int s = t + i * 256;       // slot = kb*245 + nw, kb in [0,8)
        int nw, kb;
        bf16x8 pk;
        if (s < 8 * MROWS) {
            kb = s / MROWS;
            nw = s - kb * MROWS;
            const int w = nw / N_CNT, n = nw - w * N_CNT;
            const float* g = pbase + ((size_t)(w * C_CNT + c64 * 64 + kb * 8)) * N_CNT + n;
            float ss = 0.f;
            #pragma unroll
            for (int j = 0; j < 8; ++j) {
                const float f = g[(size_t)j * N_CNT];
                ss += f * f;
                pk[j] = f2bf(f);
            }
            atomicAdd(&pns[nw], ss);
        } else {
            const int x = s - 8 * MROWS; // zero-pad rows 245..255
            nw = MROWS + (x >> 3);
            kb = x & 7;
            pk = (bf16x8){0, 0, 0, 0, 0, 0, 0, 0};
        }
        const int c32 = c64 * 2 + (kb >> 2);
        const int ln2 = ((kb & 3) << 4) | (nw & 15);
        *reinterpret_cast<bf16x8*>(
            ebase + (size_t)c32 * AFRAG_CH + (size_t)((nw >> 4) * 64 + ln2) * 16) = pk;
    }
    __syncthreads();
    if (t < MROWS) pn_part[(size_t)(e * 10 + c64) * MROWS + t] = pns[t];
}

// ---------------- gemm9: 600 blocks x 512 thr, staging halved ----------------
__global__ __launch_bounds__(512, 4)
void gemm9_kernel(const float* __restrict__ query,
                  const unsigned char* __restrict__ aimg,
                  const float* __restrict__ pn_part,
                  float* __restrict__ out)
{
    __shared__ __align__(16) unsigned char Bbuf[2 * 4096];  // 2 x (4 fj x 64 ln x 16B)
    __shared__ float qn[64];
    __shared__ float pnl[256];

    const int b = blockIdx.x;            // 600
    const int e = b & 7;                 // same e -> same XCD -> aimg L2-hot
    const int q = b >> 3;
    const int eq = e * Q_CNT + q;
    const int t = threadIdx.x;
    const int wv = t >> 6, ln = t & 63;
    const int lrow = ln & 15, lk = ln >> 4;

    const float* __restrict__ qsl = query + (size_t)eq * (C_CNT * N_CNT);

    // ---- staging role (threads 0..255): one granule (fjS, lnS) each ----
    const bool stg = t < 256;
    const int fjS = (t >> 6) & 3;        // 0..3 (valid when stg)
    const int lnS = t & 63;
    const int scol = fjS * 16 + (t & 15);
    const int scolc = (scol < N_CNT) ? scol : (N_CNT - 1);
    const int lkS = (t >> 4) & 3;
    const float* __restrict__ sbase = qsl + (size_t)(lkS * 8) * N_CNT + scolc;
    const int swoff = fjS * 1024 + lnS * 16;

    // ---- compute role: wave wv owns rows [wv*32, +32) = row-tiles wv*2+{0,1}
    const unsigned char* __restrict__ abase =
        aimg + (size_t)e * AIMG_E + (size_t)((wv * 2) * 64 + ln) * 16;

    // p-norms (hazard covered by in-loop barriers)
    if (t < MROWS) {
        float s = 0.f;
        #pragma unroll
        for (int cc = 0; cc < 10; ++cc)
            s += pn_part[(size_t)(e * 10 + cc) * MROWS + t];
        pnl[t] = sqrtf(s);
    }

    // NAMED buffers only (spill-proof regardless of unrolling)
    float vBA0, vBA1, vBA2, vBA3, vBA4, vBA5, vBA6, vBA7;
    float vBB0, vBB1, vBB2, vBB3, vBB4, vBB5, vBB6, vBB7;
    bf16x8 afrA0, afrA1, afrB0, afrB1;
    f32x4 acc[2][4];
    #pragma unroll
    for (int i = 0; i < 2; ++i)
        #pragma unroll
        for (int j = 0; j < 4; ++j) acc[i][j] = (f32x4){0.f, 0.f, 0.f, 0.f};
    float ssq = 0.f;

#define BISSUE_A(c) do { if (stg) {                                             \
    const size_t k0_ = (size_t)(c) * 32 * N_CNT;                                \
    vBA0 = sbase[k0_];              vBA1 = sbase[k0_ + 1 * N_CNT];              \
    vBA2 = sbase[k0_ + 2 * N_CNT];  vBA3 = sbase[k0_ + 3 * N_CNT];              \
    vBA4 = sbase[k0_ + 4 * N_CNT];  vBA5 = sbase[k0_ + 5 * N_CNT];              \
    vBA6 = sbase[k0_ + 6 * N_CNT];  vBA7 = sbase[k0_ + 7 * N_CNT]; } } while (0)

#define BISSUE_B(c) do { if (stg) {                                             \
    const size_t k0_ = (size_t)(c) * 32 * N_CNT;                                \
    vBB0 = sbase[k0_];              vBB1 = sbase[k0_ + 1 * N_CNT];              \
    vBB2 = sbase[k0_ + 2 * N_CNT];  vBB3 = sbase[k0_ + 3 * N_CNT];              \
    vBB4 = sbase[k0_ + 4 * N_CNT];  vBB5 = sbase[k0_ + 5 * N_CNT];              \
    vBB6 = sbase[k0_ + 6 * N_CNT];  vBB7 = sbase[k0_ + 7 * N_CNT]; } } while (0)

#define CVTW_A(bufofs) do { if (stg) {                                          \
    bf16x8 pk_;                                                                 \
    ssq += vBA0*vBA0 + vBA1*vBA1 + vBA2*vBA2 + vBA3*vBA3                        \
         + vBA4*vBA4 + vBA5*vBA5 + vBA6*vBA6 + vBA7*vBA7;                       \
    pk_[0]=f2bf(vBA0); pk_[1]=f2bf(vBA1); pk_[2]=f2bf(vBA2); pk_[3]=f2bf(vBA3); \
    pk_[4]=f2bf(vBA4); pk_[5]=f2bf(vBA5); pk_[6]=f2bf(vBA6); pk_[7]=f2bf(vBA7); \
    *reinterpret_cast<bf16x8*>(Bbuf + (bufofs) + swoff) = pk_; } } while (0)

#define CVTW_B(bufofs) do { if (stg) {                                          \
    bf16x8 pk_;                                                                 \
    ssq += vBB0*vBB0 + vBB1*vBB1 + vBB2*vBB2 + vBB3*vBB3                        \
         + vBB4*vBB4 + vBB5*vBB5 + vBB6*vBB6 + vBB7*vBB7;                       \
    pk_[0]=f2bf(vBB0); pk_[1]=f2bf(vBB1); pk_[2]=f2bf(vBB2); pk_[3]=f2bf(vBB3); \
    pk_[4]=f2bf(vBB4); pk_[5]=f2bf(vBB5); pk_[6]=f2bf(vBB6); pk_[7]=f2bf(vBB7); \
    *reinterpret_cast<bf16x8*>(Bbuf + (bufofs) + swoff) = pk_; } } while (0)

#define AISSUE_A(c) do {                                                        \
    afrA0 = *reinterpret_cast<const bf16x8*>(abase + (size_t)(c) * AFRAG_CH);   \
    afrA1 = *reinterpret_cast<const bf16x8*>(abase + (size_t)(c) * AFRAG_CH + 1024); \
} while (0)

#define AISSUE_B(c) do {                                                        \
    afrB0 = *reinterpret_cast<const bf16x8*>(abase + (size_t)(c) * AFRAG_CH);   \
    afrB1 = *reinterpret_cast<const bf16x8*>(abase + (size_t)(c) * AFRAG_CH + 1024); \
} while (0)

#define DO_MFMA(a0, a1, bufofs) do {                                            \
    bf16x8 bfr0_ = *reinterpret_cast<const bf16x8*>(Bbuf + (bufofs) + 0 * 1024 + ln * 16); \
    bf16x8 bfr1_ = *reinterpret_cast<const bf16x8*>(Bbuf + (bufofs) + 1 * 1024 + ln * 16); \
    bf16x8 bfr2_ = *reinterpret_cast<const bf16x8*>(Bbuf + (bufofs) + 2 * 1024 + ln * 16); \
    bf16x8 bfr3_ = *reinterpret_cast<const bf16x8*>(Bbuf + (bufofs) + 3 * 1024 + ln * 16); \
    acc[0][0] = __builtin_amdgcn_mfma_f32_16x16x32_bf16(a0, bfr0_, acc[0][0], 0, 0, 0); \
    acc[0][1] = __builtin_amdgcn_mfma_f32_16x16x32_bf16(a0, bfr1_, acc[0][1], 0, 0, 0); \
    acc[0][2] = __builtin_amdgcn_mfma_f32_16x16x32_bf16(a0, bfr2_, acc[0][2], 0, 0, 0); \
    acc[0][3] = __builtin_amdgcn_mfma_f32_16x16x32_bf16(a0, bfr3_, acc[0][3], 0, 0, 0); \
    acc[1][0] = __builtin_amdgcn_mfma_f32_16x16x32_bf16(a1, bfr0_, acc[1][0], 0, 0, 0); \
    acc[1][1] = __builtin_amdgcn_mfma_f32_16x16x32_bf16(a1, bfr1_, acc[1][1], 0, 0, 0); \
    acc[1][2] = __builtin_amdgcn_mfma_f32_16x16x32_bf16(a1, bfr2_, acc[1][2], 0, 0, 0); \
    acc[1][3] = __builtin_amdgcn_mfma_f32_16x16x32_bf16(a1, bfr3_, acc[1][3], 0, 0, 0); \
} while (0)

    // prologue: ch0 in vBA->Bbuf0; ch1 loads in vBB; A0 in afrA
    BISSUE_A(0);
    AISSUE_A(0);
    BISSUE_B(1);
    CVTW_A(0);
    RAW_BARRIER();

    for (int cc = 0; cc < NC32; cc += 2) {
        const bool lastpair = (cc == NC32 - 2);
        // EVEN chunk cc: compute afrA x Bbuf0; prefetch cc+2 -> vBA; A(cc+1) -> afrB
        if (!lastpair) BISSUE_A(cc + 2);
        AISSUE_B(cc + 1);
        DO_MFMA(afrA0, afrA1, 0);
        CVTW_B(4096);                    // stage chunk cc+1 (loaded >=1 phase ago)
        RAW_BARRIER();
        // ODD chunk cc+1: compute afrB x Bbuf1; prefetch cc+3 -> vBB; A(cc+2) -> afrA
        if (!lastpair) {
            BISSUE_B(cc + 3);
            AISSUE_A(cc + 2);
        }
        DO_MFMA(afrB0, afrB1, 4096);
        if (!lastpair) {
            CVTW_A(0);                   // stage chunk cc+2
            RAW_BARRIER();
        }
    }

    // ---- q-norms: stager waves reduce over lk groups, publish per column ----
    {
        float s = ssq;
        s += __shfl_xor(s, 16);
        s += __shfl_xor(s, 32);
        if (stg && lkS == 0) qn[fjS * 16 + (t & 15)] = s;
    }
    __syncthreads();

    // ---- epilogue: row = wv*32 + fi*16 + lk*4 + rr ; col = fj*16 + lrow ----
    float nq4[4];
    #pragma unroll
    for (int fj = 0; fj < 4; ++fj) {
        const int m = fj * 16 + lrow;
        nq4[fj] = (m < N_CNT) ? sqrtf(qn[m]) : 1.f;
    }
    float* __restrict__ osl = out + (size_t)eq * (W_CNT * N_CNT * N_CNT);
    #pragma unroll
    for (int fi = 0; fi < 2; ++fi) {
        #pragma unroll
        for (int rr = 0; rr < 4; ++rr) {
            const int row = wv * 32 + fi * 16 + lk * 4 + rr;
            if (row < MROWS) {
                const float np_ = pnl[row];
                #pragma unroll
                for (int fj = 0; fj < 4; ++fj) {
                    const int m = fj * 16 + lrow;
                    if (m < N_CNT) {
                        const float den = np_ * nq4[fj] + 1e-8f;
                        osl[row * N_CNT + m] = acc[fi][fj][rr] * __builtin_amdgcn_rcpf(den);
                    }
                }
            }
        }
    }
#undef BISSUE_A
#undef BISSUE_B
#undef CVTW_A
#undef CVTW_B
#undef AISSUE_A
#undef AISSUE_B
#undef DO_MFMA
}

// ---------------- tier-0 fallback (R2 kernel, no ws) -------------------------
struct SMemFB {
    unsigned char A[256 * 128];
    unsigned char B[64 * 128];
    float ns[320];
};

__global__ __launch_bounds__(512, 4)
void sim_fallback_kernel(const float* __restrict__ proto,
                         const float* __restrict__ query,
                         float* __restrict__ out)
{
    __shared__ SMemFB smf;
    const int t = threadIdx.x;
    const int e = blockIdx.x / Q_CNT;
    const int q = blockIdx.x - e * Q_CNT;
    const float* pbase = proto + (size_t)e * (W_CNT * C_CNT * N_CNT);
    const float* qbase = query + ((size_t)e * Q_CNT + q) * (C_CNT * N_CNT);
    unsigned char* lds = (unsigned char*)&smf;
    if (t < 320) smf.ns[t] = 0.f;
    if (t < 208) {
        if (t < 88) *reinterpret_cast<f32x4*>(smf.A + 245 * 128 + t * 16) = (f32x4){0.f,0.f,0.f,0.f};
        else        *reinterpret_cast<f32x4*>(smf.B + 49 * 128 + (t - 88) * 16) = (f32x4){0.f,0.f,0.f,0.f};
    }
    const int nslot5 = (t < 304);
    const float* gp[5];
    int offidx[5];
    #pragma unroll
    for (int i = 0; i < 5; ++i) {
        gp[i] = pbase; offidx[i] = 0;
        if (i < 4 || nslot5) {
            const int s = t + i * 512;
            if (s < 1960) {
                const int kb = s / 245, nw = s - kb * 245;
                const int w = nw / 49, n = nw - w * 49;
                gp[i] = pbase + ((size_t)w * C_CNT + kb * 8) * N_CNT + n;
                offidx[i] = (nw * 128 + ((kb ^ (nw & 7)) << 4)) | (nw << 16);
            } else {
                const int s2 = s - 1960;
                const int kb = s2 / 49, mq = s2 - kb * 49;
                gp[i] = qbase + (size_t)(kb * 8) * N_CNT + mq;
                offidx[i] = (32768 + mq * 128 + ((kb ^ (mq & 7)) << 4)) | ((256 + mq) << 16);
            }
        }
    }
    float v[5][8];
    float ss[5] = {0.f,0.f,0.f,0.f,0.f};
    #pragma unroll
    for (int i = 0; i < 4; ++i)
        #pragma unroll
        for (int j = 0; j < 8; ++j) v[i][j] = gp[i][(size_t)j * N_CNT];
    if (nslot5)
        #pragma unroll
        for (int j = 0; j < 8; ++j) v[4][j] = gp[4][(size_t)j * N_CNT];
    f32x4 acc[2][4];
    #pragma unroll
    for (int i = 0; i < 2; ++i)
        #pragma unroll
        for (int j = 0; j < 4; ++j) acc[i][j] = (f32x4){0.f,0.f,0.f,0.f};
    const int wv = t >> 6, ln = t & 63, lrow = ln & 15, lk = ln >> 4;
    for (int kc = 0; kc < 10; ++kc) {
        #pragma unroll
        for (int i = 0; i < 5; ++i) {
            if (i < 4 || nslot5) {
                bf16x8 pk; float s8 = 0.f;
                #pragma unroll
                for (int j = 0; j < 8; ++j) { const float f = v[i][j]; s8 += f*f; pk[j] = f2bf(f); }
                ss[i] += s8;
                *reinterpret_cast<bf16x8*>(lds + (offidx[i] & 0xFFFF)) = pk;
            }
        }
        __syncthreads();
        if (kc < 9) {
            #pragma unroll
            for (int i = 0; i < 4; ++i) {
                gp[i] += 64 * N_CNT;
                #pragma unroll
                for (int j = 0; j < 8; ++j) v[i][j] = gp[i][(size_t)j * N_CNT];
            }
            if (nslot5) {
                gp[4] += 64 * N_CNT;
                #pragma unroll
                for (int j = 0; j < 8; ++j) v[4][j] = gp[4][(size_t)j * N_CNT];
            }
        }
        #pragma unroll
        for (int ks = 0; ks < 2; ++ks) {
            bf16x8 af[2], bfr[4];
            #pragma unroll
            for (int i = 0; i < 2; ++i) {
                const int row = (wv * 2 + i) * 16 + lrow;
                const int gr = (ks * 4 + lk) ^ (row & 7);
                af[i] = *reinterpret_cast<const bf16x8*>(lds + row * 128 + gr * 16);
            }
            #pragma unroll
            for (int j = 0; j < 4; ++j) {
                const int mq = j * 16 + lrow;
                const int gr = (ks * 4 + lk) ^ (mq & 7);
                bfr[j] = *reinterpret_cast<const bf16x8*>(lds + 32768 + mq * 128 + gr * 16);
            }
            #pragma unroll
            for (int i = 0; i < 2; ++i)
                #pragma unroll
                for (int j = 0; j < 4; ++j)
                    acc[i][j] = __builtin_amdgcn_mfma_f32_16x16x32_bf16(af[i], bfr[j], acc[i][j], 0, 0, 0);
        }
        __syncthreads();
    }
    #pragma unroll
    for (int i = 0; i < 5; ++i)
        if (i < 4 || nslot5) atomicAdd(&smf.ns[offidx[i] >> 16], ss[i]);
    __syncthreads();
    float nq[4];
    #pragma unroll
    for (int j = 0; j < 4; ++j) {
        const int mq = j * 16 + lrow;
        nq[j] = (mq < N_CNT) ? sqrtf(smf.ns[256 + mq]) : 1.f;
    }
    float* obase = out + (size_t)(e * Q_CNT + q) * (W_CNT * N_CNT * N_CNT);
    #pragma unroll
    for (int i = 0; i < 2; ++i) {
        #pragma unroll
        for (int rr = 0; rr < 4; ++rr) {
            const int nw = (wv * 2 + i) * 16 + lk * 4 + rr;
            if (nw < W_CNT * N_CNT) {
                const int w = nw / 49, n = nw - w * 49;
                const float np_ = sqrtf(smf.ns[nw]);
                float* orow = obase + ((size_t)w * N_CNT + n) * N_CNT;
                #pragma unroll
                for (int j = 0; j < 4; ++j) {
                    const int mq = j * 16 + lrow;
                    if (mq < N_CNT) orow[mq] = acc[i][j][rr] / (np_ * nq[j] + 1e-8f);
                }
            }
        }
    }
}

extern "C" void kernel_launch(void* const* d_in, const int* in_sizes, int n_in,
                              void* d_out, int out_size, void* d_ws, size_t ws_size,
                              hipStream_t stream)
{
    const float* proto = (const float*)d_in[0];
    const float* query = (const float*)d_in[1];
    float* out = (float*)d_out;

    if (ws_size < WS1) {
        hipLaunchKernelGGL(sim_fallback_kernel, dim3(E_CNT * Q_CNT), dim3(512), 0, stream,
                           proto, query, out);
        return;
    }

    unsigned char* aimg = (unsigned char*)d_ws;
    float* pn_part = (float*)((unsigned char*)d_ws + PN_OFF);

    hipLaunchKernelGGL(prep_a_kernel, dim3(E_CNT * 10), dim3(256), 0, stream,
                       proto, aimg, pn_part);
    hipLaunchKernelGGL(gemm9_kernel, dim3(E_CNT * Q_CNT), dim3(512), 0, stream,
                       query, aimg, pn_part, out);
}